// Round 11
// baseline (133.917 us; speedup 1.0000x reference)
//
#include <hip/hip_runtime.h>
#include <hip/hip_bf16.h>
#include <stdint.h>

typedef __attribute__((ext_vector_type(8))) short bf16x8;
typedef __attribute__((ext_vector_type(4))) float f32x4;

#define DIN 1024
#define NROWS 8192

__device__ __forceinline__ unsigned short f2bf(float f) {
    union { float f; unsigned u; } v; v.f = f;
    unsigned r = v.u + 0x7FFFu + ((v.u >> 16) & 1u);  // RNE
    return (unsigned short)(r >> 16);
}

// 8-chunk/128B storage swizzle for Mt: within each 128B (64-col) group,
// 16B chunks permuted by chunk ^= (R & 7)
__device__ __forceinline__ size_t swz8_byte(int R, int c) {
    return ((size_t)R * DIN + (size_t)(c & ~63)) * 2
         + (size_t)(((((c >> 3) & 7) ^ (R & 7)) << 4))
         + (size_t)((c & 7) * 2);
}

__device__ __forceinline__ void gload_lds16(const void* g, void* l) {
    __builtin_amdgcn_global_load_lds(
        (const __attribute__((address_space(1))) unsigned*)g,
        (__attribute__((address_space(3))) unsigned*)l, 16, 0, 0);
}

// ---- Kernel A: vab = Wab@bag, vag = Wag@bab, c = bab.bag (no casts) ----
__global__ __launch_bounds__(256) void prep_kernel(const float* __restrict__ Wab,
                                                   const float* __restrict__ Wag,
                                                   const float* __restrict__ bab,
                                                   const float* __restrict__ bag,
                                                   float* __restrict__ ws_f) {
    int b = blockIdx.x;
    int wave = threadIdx.x >> 6, lane = threadIdx.x & 63;
    if (b == 256) {
        if (wave == 0) {
            float acc = 0.f;
            for (int j = lane; j < DIN; j += 64) acc += bab[j] * bag[j];
            for (int off = 32; off; off >>= 1) acc += __shfl_xor(acc, off);
            if (lane == 0) ws_f[2048] = acc;
        }
        return;
    }
    int r = b * 4 + wave;
    const float* w1r = Wab + (size_t)r * DIN;
    const float* w2r = Wag + (size_t)r * DIN;
    float a1 = 0.f, a2 = 0.f;
#pragma unroll
    for (int it = 0; it < 4; ++it) {
        int col = it * 256 + lane * 4;
        float4 w1 = *reinterpret_cast<const float4*>(w1r + col);
        float4 bg = *reinterpret_cast<const float4*>(bag + col);
        float4 w2 = *reinterpret_cast<const float4*>(w2r + col);
        float4 bb = *reinterpret_cast<const float4*>(bab + col);
        a1 += w1.x * bg.x + w1.y * bg.y + w1.z * bg.z + w1.w * bg.w;
        a2 += w2.x * bb.x + w2.y * bb.y + w2.z * bb.z + w2.w * bb.w;
    }
#pragma unroll
    for (int off = 32; off; off >>= 1) { a1 += __shfl_xor(a1, off); a2 += __shfl_xor(a2, off); }
    if (lane == 0) { ws_f[r] = a1; ws_f[1024 + r] = a2; }
}

// ---- Kernel B: Mt[l,k] = Wag[l,:].Wab[k,:] from fp32 W directly; 64x64 tile,
//      8 waves = 2 K-groups x 4; reg-stage fp32 -> cvt -> swizzled LDS; Mt out swz8 ----
__global__ __launch_bounds__(512) void mt_kernel(const float* __restrict__ Wag_,
                                                 const float* __restrict__ Wab_,
                                                 unsigned short* __restrict__ Mt) {
    __shared__ unsigned short sm[2][2][2][2048];   // [grp][buf][op][64*32 shorts] = 32 KB
    int tid = threadIdx.x;
    int wave = tid >> 6, grp = wave >> 2, w4 = wave & 3;
    int lane = tid & 63, kg = lane >> 4, cl = lane & 15;
    int wr = w4 >> 1, wc = w4 & 1;
    int br = blockIdx.x >> 4, bc = blockIdx.x & 15;
    int u = tid & 255;

    int offA[2], offB[2];   // short-unit offsets
#pragma unroll
    for (int m = 0; m < 2; ++m) { int row = wr * 32 + m * 16 + cl; offA[m] = row * 32 + ((kg ^ (row & 3)) << 3); }
#pragma unroll
    for (int n = 0; n < 2; ++n) { int row = wc * 32 + n * 16 + cl; offB[n] = row * 32 + ((kg ^ (row & 3)) << 3); }

    float4 raA[2], raB[2];
#define LOADMT(t)                                                                          \
    _Pragma("unroll")                                                                      \
    for (int it = 0; it < 2; ++it) {                                                       \
        int un = u + it * 256, rowu = un >> 3, c4 = un & 7;                                \
        raA[it] = *reinterpret_cast<const float4*>(Wag_ + (size_t)(br * 64 + rowu) * DIN + grp * 512 + (t) * 32 + c4 * 4); \
        raB[it] = *reinterpret_cast<const float4*>(Wab_ + (size_t)(bc * 64 + rowu) * DIN + grp * 512 + (t) * 32 + c4 * 4); \
    }
#define WRITEMT(buf, t)                                                                    \
    _Pragma("unroll")                                                                      \
    for (int it = 0; it < 2; ++it) {                                                       \
        int un = u + it * 256, rowu = un >> 3, c4 = un & 7;                                \
        int slot = rowu * 32 + ((((c4 >> 1) ^ (rowu & 3))) << 3) + (c4 & 1) * 4;           \
        ushort4 hA; hA.x = f2bf(raA[it].x); hA.y = f2bf(raA[it].y); hA.z = f2bf(raA[it].z); hA.w = f2bf(raA[it].w); \
        *reinterpret_cast<ushort4*>(&sm[grp][buf][0][slot]) = hA;                          \
        ushort4 hB; hB.x = f2bf(raB[it].x); hB.y = f2bf(raB[it].y); hB.z = f2bf(raB[it].z); hB.w = f2bf(raB[it].w); \
        *reinterpret_cast<ushort4*>(&sm[grp][buf][1][slot]) = hB;                          \
    }

    f32x4 acc[2][2] = {};
    LOADMT(0);
    WRITEMT(0, 0);
    __syncthreads();
    for (int t = 0; t < 16; ++t) {
        int p = t & 1;
        if (t < 15) { LOADMT(t + 1); }
        bf16x8 af[2], bfr[2];
#pragma unroll
        for (int m = 0; m < 2; ++m) af[m] = *reinterpret_cast<const bf16x8*>(&sm[grp][p][0][offA[m]]);
#pragma unroll
        for (int n = 0; n < 2; ++n) bfr[n] = *reinterpret_cast<const bf16x8*>(&sm[grp][p][1][offB[n]]);
#pragma unroll
        for (int m = 0; m < 2; ++m)
#pragma unroll
            for (int n = 0; n < 2; ++n)
                acc[m][n] = __builtin_amdgcn_mfma_f32_16x16x32_bf16(af[m], bfr[n], acc[m][n], 0, 0, 0);
        if (t < 15) { WRITEMT(p ^ 1, t + 1); }
        __syncthreads();
    }
#undef LOADMT
#undef WRITEMT
    // cross-group K reduction via LDS (aliased over staging buffers)
    float* red = (float*)sm;   // [64][68] padded
    if (grp == 1) {
#pragma unroll
        for (int m = 0; m < 2; ++m)
#pragma unroll
            for (int n = 0; n < 2; ++n)
#pragma unroll
                for (int j = 0; j < 4; ++j)
                    red[(wr * 32 + m * 16 + kg * 4 + j) * 68 + wc * 32 + n * 16 + cl] = acc[m][n][j];
    }
    __syncthreads();
    if (grp == 0) {
#pragma unroll
        for (int m = 0; m < 2; ++m)
#pragma unroll
            for (int n = 0; n < 2; ++n)
#pragma unroll
                for (int j = 0; j < 4; ++j) {
                    int rl = wr * 32 + m * 16 + kg * 4 + j, cll = wc * 32 + n * 16 + cl;
                    float v = acc[m][n][j] + red[rl * 68 + cll];
                    int R = br * 64 + rl, C = bc * 64 + cll;
                    *(unsigned short*)((char*)Mt + swz8_byte(R, C)) = f2bf(v);
                }
    }
}

// ---- Kernel C (fused): R4-structure GEMM (128^2 tile, BK=32, KS=2, 4 blk/CU) with
//      in-loop streaming: h2 slice (col-chunk per block) + Term2 (from fp32 A regs,
//      cblk==0) + vag/Term1 epilogue. No gABh, no separate stream pass. ----
__global__ __launch_bounds__(256, 4) void fused_kernel(const float* __restrict__ gAB,
                                                       const float* __restrict__ gAG,
                                                       const float* __restrict__ sAB,
                                                       const float* __restrict__ sAG,
                                                       const unsigned short* __restrict__ Mt,
                                                       const float* __restrict__ ws_f,
                                                       float* __restrict__ out) {
    __shared__ unsigned short lds_a[2][128 * 32];   // 8 KB per buffer
    __shared__ unsigned short lds_b[2][128 * 32];
    constexpr int NSTEP = 16;                       // K/2 = 512, BK = 32
    int b = blockIdx.x;
    int x = b & 7, s = b >> 3;          // XCD map: same rblk's 16 blocks share an XCD
    int rblk = x + 8 * (s & 7);         // 0..63
    int u2 = s >> 3;                    // 0..15
    int ks = u2 & 1;
    int cblk = u2 >> 1;                 // 0..7
    int tid = threadIdx.x, wave = tid >> 6, lane = tid & 63;
    int wr = wave >> 1, wc = wave & 1;
    int kg = lane >> 4, cl = lane & 15;
    int row0 = rblk * 128, col0 = cblk * 128;
    int hcol0 = ((cblk << 1) | ks) * 64;            // h2 col-chunk (16 x 64 = 1024)

    int offA[4], offB[4];   // byte offsets
#pragma unroll
    for (int m = 0; m < 4; ++m) { int row = wr * 64 + m * 16 + cl; offA[m] = row * 64 + ((kg ^ (row & 3)) << 4); }
#pragma unroll
    for (int n = 0; n < 4; ++n) { int row = wc * 64 + n * 16 + cl; offB[n] = row * 64 + ((kg ^ (row & 3)) << 4); }

    const float* Af = gAB + (size_t)row0 * DIN + ks * 512;
    const char* Bb = (const char*)Mt + ((size_t)col0 * DIN + ks * 512) * 2;
    const float* vab = ws_f;
    const float* vag = ws_f + 1024;

    // h2 streaming pointers: row = row0 + (tid>>1), col pair = hcol0 + t*4 + (tid&1)*2
    const float* saRow = sAB + (size_t)(row0 + (tid >> 1)) * DIN + hcol0 + (tid & 1) * 2;
    const float* sgRow = sAG + (size_t)(row0 + (tid >> 1)) * DIN + hcol0 + (tid & 1) * 2;

    f32x4 acc[4][4] = {};
    float4 ra[4];
    float tacc[4] = {0.f, 0.f, 0.f, 0.f};   // Term2 partials, rows (tid>>3)+it*32
    float hacc = 0.f;                        // h2 partial, row tid>>1

#define LOADA(t)                                                                           \
    _Pragma("unroll")                                                                      \
    for (int it = 0; it < 4; ++it) {                                                       \
        int un = tid + it * 256;                                                           \
        ra[it] = *reinterpret_cast<const float4*>(Af + (size_t)(un >> 3) * DIN + (t) * 32 + (un & 7) * 4); \
    }
#define WRITEA(buf, t) do {                                                                \
    float4 vv = *reinterpret_cast<const float4*>(vab + ks * 512 + (t) * 32 + (tid & 7) * 4); \
    _Pragma("unroll")                                                                      \
    for (int it = 0; it < 4; ++it) {                                                       \
        int un = tid + it * 256, row_ = un >> 3, c4 = un & 7;                              \
        if (cblk == 0)                                                                     \
            tacc[it] += ra[it].x * vv.x + ra[it].y * vv.y + ra[it].z * vv.z + ra[it].w * vv.w; \
        ushort4 h; h.x = f2bf(ra[it].x); h.y = f2bf(ra[it].y); h.z = f2bf(ra[it].z); h.w = f2bf(ra[it].w); \
        *reinterpret_cast<ushort4*>((char*)&lds_a[buf][0] + row_ * 64 +                    \
                                    ((((c4 >> 1) ^ (row_ & 3))) << 4) + (c4 & 1) * 8) = h; \
    } } while (0)
#define STAGE_B(buf, t)                                                                    \
    _Pragma("unroll")                                                                      \
    for (int it = 0; it < 2; ++it) {                                                       \
        int un = tid + it * 256, row_ = un >> 2, s_ = un & 3;                              \
        int pg = ((((t) & 1) << 2) ^ (row_ & 4)) | s_;                                     \
        gload_lds16(Bb + (size_t)row_ * 2048 + ((t) >> 1) * 128 + pg * 16,                 \
                    (char*)&lds_b[buf][0] + un * 16);                                      \
    }

    // prologue: tile 0 into buf 0
    STAGE_B(0, 0);
    LOADA(0);
    WRITEA(0, 0);
    __syncthreads();

    for (int t = 0; t < NSTEP; ++t) {
        int p = t & 1;
        if (t < NSTEP - 1) {
            STAGE_B(p ^ 1, t + 1);
            LOADA(t + 1);
        }
        // h2 streaming loads (independent; consumed after MFMA)
        float2 sa2 = *reinterpret_cast<const float2*>(saRow + t * 4);
        float2 sg2 = *reinterpret_cast<const float2*>(sgRow + t * 4);
        bf16x8 bfr[4];
#pragma unroll
        for (int n = 0; n < 4; ++n) bfr[n] = *reinterpret_cast<const bf16x8*>((char*)&lds_b[p][0] + offB[n]);
#pragma unroll
        for (int m = 0; m < 4; ++m) {
            bf16x8 af = *reinterpret_cast<const bf16x8*>((char*)&lds_a[p][0] + offA[m]);
#pragma unroll
            for (int n = 0; n < 4; ++n)
                acc[m][n] = __builtin_amdgcn_mfma_f32_16x16x32_bf16(af, bfr[n], acc[m][n], 0, 0, 0);
        }
        hacc += sa2.x * sg2.x + sa2.y * sg2.y;
        if (t < NSTEP - 1) { WRITEA(p ^ 1, t + 1); }
        __syncthreads();
    }
#undef LOADA
#undef WRITEA
#undef STAGE_B

    // ---- per-row partial fold: rowacc in LDS (reuse lds_a) ----
    float* rowacc = (float*)&lds_a[0][0];
    if (tid < 128) rowacc[tid] = 0.f;
    __syncthreads();
    if (cblk == 0) {
#pragma unroll
        for (int it = 0; it < 4; ++it)
            atomicAdd(&rowacc[(tid >> 3) + it * 32], tacc[it]);
    }
    atomicAdd(&rowacc[tid >> 1], hacc);
    __syncthreads();
    if (tid < 128) {
        float v = rowacc[tid];
        if (cblk == 0 && ks == 0) v += ws_f[2048];   // + c once per row
        atomicAdd(out + row0 + tid, 0.5f * v);
    }

    // ---- Term1 (+ vag at ks==0) epilogue ----
#pragma unroll
    for (int m = 0; m < 4; ++m)
#pragma unroll
        for (int j = 0; j < 4; ++j) {
            int row = row0 + wr * 64 + m * 16 + kg * 4 + j;
            const float* gr = gAG + (size_t)row * DIN;
            float t = 0.f;
#pragma unroll
            for (int n = 0; n < 4; ++n) {
                int col = col0 + wc * 64 + n * 16 + cl;
                float addv = (ks == 0) ? vag[col] : 0.f;
                t += gr[col] * (acc[m][n][j] + addv);
            }
            t += __shfl_xor(t, 1);
            t += __shfl_xor(t, 2);
            t += __shfl_xor(t, 4);
            t += __shfl_xor(t, 8);
            if (cl == 0) atomicAdd(out + row, 0.5f * t);
        }
}

extern "C" void kernel_launch(void* const* d_in, const int* in_sizes, int n_in,
                              void* d_out, int out_size, void* d_ws, size_t ws_size,
                              hipStream_t stream) {
    const float* gAB = (const float*)d_in[0];
    const float* gAG = (const float*)d_in[1];
    const float* Wab = (const float*)d_in[2];
    const float* Wag = (const float*)d_in[3];
    const float* bab = (const float*)d_in[4];
    const float* bag = (const float*)d_in[5];
    const float* sAB = (const float*)d_in[6];
    const float* sAG = (const float*)d_in[7];
    float* out = (float*)d_out;

    // ws layout: ws_f 16KB | Mt 2MB
    float* ws_f = (float*)d_ws;
    unsigned short* Mt = (unsigned short*)((char*)d_ws + 16384);

    hipMemsetAsync(d_out, 0, (size_t)out_size * sizeof(float), stream);
    prep_kernel<<<257, 256, 0, stream>>>(Wab, Wag, bab, bag, ws_f);
    mt_kernel<<<256, 512, 0, stream>>>(Wag, Wab, Mt);
    fused_kernel<<<1024, 256, 0, stream>>>(gAB, gAG, sAB, sAG, Mt, ws_f, out);
}

// Round 12
// 89.722 us; speedup vs baseline: 1.4926x; 1.4926x over previous
//
#include <hip/hip_runtime.h>
#include <hip/hip_bf16.h>
#include <stdint.h>

typedef __attribute__((ext_vector_type(8))) short bf16x8;
typedef __attribute__((ext_vector_type(4))) float f32x4;

#define DIN 1024
#define NROWS 8192

__device__ __forceinline__ unsigned short f2bf(float f) {
    union { float f; unsigned u; } v; v.f = f;
    unsigned r = v.u + 0x7FFFu + ((v.u >> 16) & 1u);  // RNE
    return (unsigned short)(r >> 16);
}

// 8-chunk/128B storage swizzle for Mt and gABh: within each 128B (64-col) group,
// 16B chunks permuted by chunk ^= (R & 7)
__device__ __forceinline__ size_t swz8_byte(int R, int c) {
    return ((size_t)R * DIN + (size_t)(c & ~63)) * 2
         + (size_t)(((((c >> 3) & 7) ^ (R & 7)) << 4))
         + (size_t)((c & 7) * 2);
}

__device__ __forceinline__ void gload_lds16(const void* g, void* l) {
    __builtin_amdgcn_global_load_lds(
        (const __attribute__((address_space(1))) unsigned*)g,
        (__attribute__((address_space(3))) unsigned*)l, 16, 0, 0);
}

// ---- Kernel A: vab = Wab@bag, vag = Wag@bab, c = bab.bag ----
__global__ __launch_bounds__(256) void prep_kernel(const float* __restrict__ Wab,
                                                   const float* __restrict__ Wag,
                                                   const float* __restrict__ bab,
                                                   const float* __restrict__ bag,
                                                   float* __restrict__ ws_f) {
    int b = blockIdx.x;
    int wave = threadIdx.x >> 6, lane = threadIdx.x & 63;
    if (b == 256) {
        if (wave == 0) {
            float acc = 0.f;
            for (int j = lane; j < DIN; j += 64) acc += bab[j] * bag[j];
            for (int off = 32; off; off >>= 1) acc += __shfl_xor(acc, off);
            if (lane == 0) ws_f[2048] = acc;
        }
        return;
    }
    int r = b * 4 + wave;
    const float* w1r = Wab + (size_t)r * DIN;
    const float* w2r = Wag + (size_t)r * DIN;
    float a1 = 0.f, a2 = 0.f;
#pragma unroll
    for (int it = 0; it < 4; ++it) {
        int col = it * 256 + lane * 4;
        float4 w1 = *reinterpret_cast<const float4*>(w1r + col);
        float4 bg = *reinterpret_cast<const float4*>(bag + col);
        float4 w2 = *reinterpret_cast<const float4*>(w2r + col);
        float4 bb = *reinterpret_cast<const float4*>(bab + col);
        a1 += w1.x * bg.x + w1.y * bg.y + w1.z * bg.z + w1.w * bg.w;
        a2 += w2.x * bb.x + w2.y * bb.y + w2.z * bb.z + w2.w * bb.w;
    }
#pragma unroll
    for (int off = 32; off; off >>= 1) { a1 += __shfl_xor(a1, off); a2 += __shfl_xor(a2, off); }
    if (lane == 0) { ws_f[r] = a1; ws_f[1024 + r] = a2; }
}

// ---- Kernel B: Mt[l,k] = Wag[l,:].Wab[k,:] from fp32 W; writes Mt in swz8 ----
__global__ __launch_bounds__(512) void mt_kernel(const float* __restrict__ Wag_,
                                                 const float* __restrict__ Wab_,
                                                 unsigned short* __restrict__ Mt) {
    __shared__ unsigned short sm[2][2][2][2048];   // [grp][buf][op][64*32 shorts] = 32 KB
    int tid = threadIdx.x;
    int wave = tid >> 6, grp = wave >> 2, w4 = wave & 3;
    int lane = tid & 63, kg = lane >> 4, cl = lane & 15;
    int wr = w4 >> 1, wc = w4 & 1;
    int br = blockIdx.x >> 4, bc = blockIdx.x & 15;
    int u = tid & 255;

    int offA[2], offB[2];   // short-unit offsets
#pragma unroll
    for (int m = 0; m < 2; ++m) { int row = wr * 32 + m * 16 + cl; offA[m] = row * 32 + ((kg ^ (row & 3)) << 3); }
#pragma unroll
    for (int n = 0; n < 2; ++n) { int row = wc * 32 + n * 16 + cl; offB[n] = row * 32 + ((kg ^ (row & 3)) << 3); }

    float4 raA[2], raB[2];
#define LOADMT(t)                                                                          \
    _Pragma("unroll")                                                                      \
    for (int it = 0; it < 2; ++it) {                                                       \
        int un = u + it * 256, rowu = un >> 3, c4 = un & 7;                                \
        raA[it] = *reinterpret_cast<const float4*>(Wag_ + (size_t)(br * 64 + rowu) * DIN + grp * 512 + (t) * 32 + c4 * 4); \
        raB[it] = *reinterpret_cast<const float4*>(Wab_ + (size_t)(bc * 64 + rowu) * DIN + grp * 512 + (t) * 32 + c4 * 4); \
    }
#define WRITEMT(buf, t)                                                                    \
    _Pragma("unroll")                                                                      \
    for (int it = 0; it < 2; ++it) {                                                       \
        int un = u + it * 256, rowu = un >> 3, c4 = un & 7;                                \
        int slot = rowu * 32 + ((((c4 >> 1) ^ (rowu & 3))) << 3) + (c4 & 1) * 4;           \
        ushort4 hA; hA.x = f2bf(raA[it].x); hA.y = f2bf(raA[it].y); hA.z = f2bf(raA[it].z); hA.w = f2bf(raA[it].w); \
        *reinterpret_cast<ushort4*>(&sm[grp][buf][0][slot]) = hA;                          \
        ushort4 hB; hB.x = f2bf(raB[it].x); hB.y = f2bf(raB[it].y); hB.z = f2bf(raB[it].z); hB.w = f2bf(raB[it].w); \
        *reinterpret_cast<ushort4*>(&sm[grp][buf][1][slot]) = hB;                          \
    }

    f32x4 acc[2][2] = {};
    LOADMT(0);
    WRITEMT(0, 0);
    __syncthreads();
    for (int t = 0; t < 16; ++t) {
        int p = t & 1;
        if (t < 15) { LOADMT(t + 1); }
        bf16x8 af[2], bfr[2];
#pragma unroll
        for (int m = 0; m < 2; ++m) af[m] = *reinterpret_cast<const bf16x8*>(&sm[grp][p][0][offA[m]]);
#pragma unroll
        for (int n = 0; n < 2; ++n) bfr[n] = *reinterpret_cast<const bf16x8*>(&sm[grp][p][1][offB[n]]);
#pragma unroll
        for (int m = 0; m < 2; ++m)
#pragma unroll
            for (int n = 0; n < 2; ++n)
                acc[m][n] = __builtin_amdgcn_mfma_f32_16x16x32_bf16(af[m], bfr[n], acc[m][n], 0, 0, 0);
        if (t < 15) { WRITEMT(p ^ 1, t + 1); }
        __syncthreads();
    }
#undef LOADMT
#undef WRITEMT
    float* red = (float*)sm;   // [64][68] padded
    if (grp == 1) {
#pragma unroll
        for (int m = 0; m < 2; ++m)
#pragma unroll
            for (int n = 0; n < 2; ++n)
#pragma unroll
                for (int j = 0; j < 4; ++j)
                    red[(wr * 32 + m * 16 + kg * 4 + j) * 68 + wc * 32 + n * 16 + cl] = acc[m][n][j];
    }
    __syncthreads();
    if (grp == 0) {
#pragma unroll
        for (int m = 0; m < 2; ++m)
#pragma unroll
            for (int n = 0; n < 2; ++n)
#pragma unroll
                for (int j = 0; j < 4; ++j) {
                    int rl = wr * 32 + m * 16 + kg * 4 + j, cll = wc * 32 + n * 16 + cl;
                    float v = acc[m][n][j] + red[rl * 68 + cll];
                    int R = br * 64 + rl, C = bc * 64 + cll;
                    *(unsigned short*)((char*)Mt + swz8_byte(R, C)) = f2bf(v);
                }
    }
}

// ---- Kernel C: streaming — h2 + Term2 + c; casts gAB -> gABh (swz8) ----
__global__ __launch_bounds__(256) void stream_kernel(const float* __restrict__ gAB,
                                                     const float* __restrict__ sAB,
                                                     const float* __restrict__ sAG,
                                                     const float* __restrict__ ws_f,
                                                     unsigned short* __restrict__ gABh,
                                                     float* __restrict__ out,
                                                     int writecast) {
    int wave = threadIdx.x >> 6, lane = threadIdx.x & 63;
    int row = blockIdx.x * 4 + wave;
    const float* ga = gAB + (size_t)row * DIN;
    const float* sa = sAB + (size_t)row * DIN;
    const float* sg = sAG + (size_t)row * DIN;
    char* gh = (char*)gABh + (size_t)row * DIN * 2;
    int fr8 = row & 7;
    float acc = 0.f;
#pragma unroll
    for (int cc = 0; cc < 4; ++cc) {
        int col = cc * 256 + lane * 4;
        float4 a = *reinterpret_cast<const float4*>(ga + col);
        float4 x = *reinterpret_cast<const float4*>(sa + col);
        float4 y = *reinterpret_cast<const float4*>(sg + col);
        float4 v = *reinterpret_cast<const float4*>(ws_f + col);   // vab
        acc += x.x * y.x + x.y * y.y + x.z * y.z + x.w * y.w;
        acc += a.x * v.x + a.y * v.y + a.z * v.z + a.w * v.w;
        if (writecast) {
            ushort4 h; h.x = f2bf(a.x); h.y = f2bf(a.y); h.z = f2bf(a.z); h.w = f2bf(a.w);
            *reinterpret_cast<ushort4*>(gh + (col & ~63) * 2 + ((((col >> 3) & 7) ^ fr8) << 4) + (col & 7) * 2) = h;
        }
    }
#pragma unroll
    for (int off = 32; off; off >>= 1) acc += __shfl_xor(acc, off);
    if (lane == 0) out[row] = 0.5f * (acc + ws_f[2048]);
}

// ---- Kernel D: 8-phase 256x256 GEMM (T2+T3+T4+T5), KSPLIT=2, 1 block/CU ----
// Stage-halves defined by first-read region so the 2-tile-ahead pipeline never
// overwrites live data:  SA0 = A rows {0-63,128-191} (read ph1-2), SA1 = rest
// (ph3-4); SB0 = B rows (row&63)<32 (ph1,3), SB1 = rest (ph2,4).
// Per tile: ph1 stage SB1(t+1); ph2 SA1(t+1); ph3 SA0(t+2); ph4 SB0(t+2) +
// vmcnt(4) boundary (FIFO => all of tile t+1 landed, t+2's 2 halves in flight).
__global__ __launch_bounds__(512, 1) void gemm8(const unsigned short* __restrict__ gABh,
                                                const float* __restrict__ gAG,
                                                const unsigned short* __restrict__ Mt,
                                                const float* __restrict__ ws_f,
                                                float* __restrict__ out) {
    __shared__ unsigned short lds_a[2][2][128 * 64];   // [dbuf][half] 16 KB each = 64 KB
    __shared__ unsigned short lds_b[2][2][128 * 64];   // 64 KB (total 128 KB)
    constexpr int NSTEP = 8;   // K-tiles of 64 within KLEN=512
    int b = blockIdx.x;
    int x = b & 7, s = b >> 3;
    int rblk = x + 8 * (s & 3);       // 0..31
    int rem = s >> 2;
    int ks = rem & 1, cblk = rem >> 1;
    int tid = threadIdx.x, wave = tid >> 6, lane = tid & 63;
    int wr = wave >> 2, wc = wave & 3;        // 2(M) x 4(N)
    int kg = lane >> 4, cl = lane & 15;
    int row0 = rblk * 256, col0 = cblk * 256;

    const char* Ab = (const char*)gABh + (size_t)row0 * 2048 + ks * 1024;
    const char* Bb = (const char*)Mt + (size_t)col0 * 2048 + ks * 1024;

#define STAGE_Ah(dbuf, half, t) do {                                             \
    _Pragma("unroll")                                                            \
    for (int it = 0; it < 2; ++it) {                                             \
        int u = tid + it * 512;                                                  \
        int rp = u >> 3, sc = u & 7;                                             \
        int R = rp + (rp & 64) + (half) * 64;                                    \
        gload_lds16(Ab + (size_t)R * 2048 + (t) * 128 + sc * 16,                 \
                    (char*)&lds_a[dbuf][half][0] + u * 16);                      \
    } } while (0)
#define STAGE_Bh(dbuf, half, t) do {                                             \
    _Pragma("unroll")                                                            \
    for (int it = 0; it < 2; ++it) {                                             \
        int u = tid + it * 512;                                                  \
        int rp = u >> 3, sc = u & 7;                                             \
        int R = ((rp >> 5) << 6) + (rp & 31) + (half) * 32;                      \
        gload_lds16(Bb + (size_t)R * 2048 + (t) * 128 + sc * 16,                 \
                    (char*)&lds_b[dbuf][half][0] + u * 16);                      \
    } } while (0)

    f32x4 acc[8][4] = {};

#define PHASE(p, mh, nh, STAGE_STMT, PRE_TRAIL) do {                             \
    bf16x8 af[4][2], bv[2][2];                                                   \
    _Pragma("unroll")                                                            \
    for (int m4 = 0; m4 < 4; ++m4) {                                             \
        int rp = wr * 64 + m4 * 16 + cl;                                         \
        _Pragma("unroll")                                                        \
        for (int kk = 0; kk < 2; ++kk)                                           \
            af[m4][kk] = *reinterpret_cast<const bf16x8*>(                       \
                &lds_a[p][mh][rp * 64 + (((kk * 4 + kg) ^ (cl & 7)) << 3)]);     \
    }                                                                            \
    _Pragma("unroll")                                                            \
    for (int n2 = 0; n2 < 2; ++n2) {                                             \
        int rp = wc * 32 + n2 * 16 + cl;                                         \
        _Pragma("unroll")                                                        \
        for (int kk = 0; kk < 2; ++kk)                                           \
            bv[n2][kk] = *reinterpret_cast<const bf16x8*>(                       \
                &lds_b[p][nh][rp * 64 + (((kk * 4 + kg) ^ (cl & 7)) << 3)]);     \
    }                                                                            \
    STAGE_STMT;                                                                  \
    __builtin_amdgcn_sched_barrier(0);                                           \
    __builtin_amdgcn_s_barrier();                                                \
    __builtin_amdgcn_sched_barrier(0);                                           \
    __builtin_amdgcn_s_setprio(1);                                               \
    _Pragma("unroll")                                                            \
    for (int m4 = 0; m4 < 4; ++m4)                                               \
        _Pragma("unroll")                                                        \
        for (int n2 = 0; n2 < 2; ++n2)                                           \
            _Pragma("unroll")                                                    \
            for (int kk = 0; kk < 2; ++kk)                                       \
                acc[(mh) * 4 + m4][(nh) * 2 + n2] =                              \
                    __builtin_amdgcn_mfma_f32_16x16x32_bf16(                     \
                        af[m4][kk], bv[n2][kk], acc[(mh) * 4 + m4][(nh) * 2 + n2], 0, 0, 0); \
    __builtin_amdgcn_s_setprio(0);                                               \
    PRE_TRAIL;                                                                   \
    __builtin_amdgcn_sched_barrier(0);                                           \
    __builtin_amdgcn_s_barrier();                                                \
    __builtin_amdgcn_sched_barrier(0);                                           \
} while (0)

    // prologue: tile0 all 4 halves + tile1's SA0,SB0 (FIFO-ordered)
    STAGE_Ah(0, 0, 0);
    STAGE_Bh(0, 0, 0);
    STAGE_Bh(0, 1, 0);
    STAGE_Ah(0, 1, 0);
    STAGE_Ah(1, 0, 1);
    STAGE_Bh(1, 0, 1);
    asm volatile("s_waitcnt vmcnt(4)" ::: "memory");   // tile 0 landed; tile1 halves in flight
    __builtin_amdgcn_sched_barrier(0);
    __builtin_amdgcn_s_barrier();
    __builtin_amdgcn_sched_barrier(0);

    for (int t = 0; t < NSTEP; ++t) {
        int p = t & 1;
        bool s1 = (t + 1 < NSTEP), s2 = (t + 2 < NSTEP);
        PHASE(p, 0, 0, if (s1) STAGE_Bh(p ^ 1, 1, t + 1), (void)0);
        PHASE(p, 0, 1, if (s1) STAGE_Ah(p ^ 1, 1, t + 1), (void)0);
        PHASE(p, 1, 0, if (s2) STAGE_Ah(p, 0, t + 2), (void)0);
        if (s2) {
            PHASE(p, 1, 1, STAGE_Bh(p, 0, t + 2),
                  asm volatile("s_waitcnt vmcnt(4)" ::: "memory"));
        } else {
            PHASE(p, 1, 1, (void)0,
                  asm volatile("s_waitcnt vmcnt(0)" ::: "memory"));
        }
    }
#undef PHASE
#undef STAGE_Ah
#undef STAGE_Bh

    // epilogue: Term1 (all ks) + Term3 (ks==0 only); gAG kept fp32
    const float* vag = ws_f + 1024;
#pragma unroll
    for (int m = 0; m < 8; ++m)
#pragma unroll
        for (int j = 0; j < 4; ++j) {
            int row = row0 + wr * 128 + m * 16 + kg * 4 + j;
            const float* gr = gAG + (size_t)row * DIN;
            float tt = 0.f;
#pragma unroll
            for (int n = 0; n < 4; ++n) {
                int col = col0 + wc * 64 + n * 16 + cl;
                float addv = (ks == 0) ? vag[col] : 0.f;
                tt += gr[col] * (acc[m][n][j] + addv);
            }
            tt += __shfl_xor(tt, 1);
            tt += __shfl_xor(tt, 2);
            tt += __shfl_xor(tt, 4);
            tt += __shfl_xor(tt, 8);
            if (cl == 0) atomicAdd(out + row, 0.5f * tt);
        }
}

// ---- fallback GEMM (small ws): fp32 reg-stage 128^2 (dead in practice) ----
__global__ __launch_bounds__(256, 4) void gemm_fb(const float* __restrict__ gAB,
                                                  const float* __restrict__ gAG,
                                                  const unsigned short* __restrict__ Mt,
                                                  const float* __restrict__ ws_f,
                                                  float* __restrict__ out) {
    __shared__ unsigned short lds_a[2][128 * 32];
    __shared__ unsigned short lds_b[2][128 * 32];
    constexpr int KSPLIT = 2, KLEN = DIN / KSPLIT, NSTEP = KLEN / 32;
    int b = blockIdx.x;
    int x = b & 7, s = b >> 3;
    int rblk = x + 8 * (s & 7);
    int u2 = s >> 3;
    int ks = u2 & (KSPLIT - 1);
    int cblk = u2 / KSPLIT;
    int tid = threadIdx.x, wave = tid >> 6, lane = tid & 63;
    int wr = wave >> 1, wc = wave & 1;
    int kg = lane >> 4, cl = lane & 15;
    int row0 = rblk * 128, col0 = cblk * 128;

    int offA[4], offB[4];
#pragma unroll
    for (int m = 0; m < 4; ++m) { int row = wr * 64 + m * 16 + cl; offA[m] = row * 64 + ((kg ^ (row & 3)) << 4); }
#pragma unroll
    for (int n = 0; n < 4; ++n) { int row = wc * 64 + n * 16 + cl; offB[n] = row * 64 + ((kg ^ (row & 3)) << 4); }

    const float* Af = gAB + (size_t)row0 * DIN + ks * KLEN;
    const char* Bb = (const char*)Mt + ((size_t)col0 * DIN + ks * KLEN) * 2;

    f32x4 acc[4][4] = {};
    float4 ra[4];
#define STAGE_A(buf, t)                                                             \
    _Pragma("unroll")                                                               \
    for (int it = 0; it < 4; ++it) {                                                \
        int u = tid + it * 256, row_ = u >> 3, c4 = u & 7;                          \
        ra[it] = *reinterpret_cast<const float4*>(Af + (size_t)row_ * DIN + (t) * 32 + c4 * 4); \
    }                                                                               \
    _Pragma("unroll")                                                               \
    for (int it = 0; it < 4; ++it) {                                                \
        int u = tid + it * 256, row_ = u >> 3, c4 = u & 7;                          \
        ushort4 h; h.x = f2bf(ra[it].x); h.y = f2bf(ra[it].y); h.z = f2bf(ra[it].z); h.w = f2bf(ra[it].w); \
        *reinterpret_cast<ushort4*>((char*)&lds_a[buf][0] + row_ * 64 +             \
                                    (((c4 >> 1) ^ (row_ & 3)) << 4) + (c4 & 1) * 8) = h; \
    }
#define STAGE_Bm(buf, t)                                                            \
    _Pragma("unroll")                                                               \
    for (int it = 0; it < 2; ++it) {                                                \
        int u = tid + it * 256, row_ = u >> 2, s_ = u & 3;                          \
        int pg = ((((t) & 1) << 2) ^ (row_ & 4)) | s_;                              \
        gload_lds16(Bb + (size_t)row_ * 2048 + ((t) >> 1) * 128 + pg * 16,          \
                    (char*)&lds_b[buf][0] + u * 16);                                \
    }
    STAGE_A(0, 0);
    STAGE_Bm(0, 0);
    for (int t = 0; t < NSTEP; ++t) {
        int p = t & 1;
        __syncthreads();
        if (t < NSTEP - 1) { STAGE_Bm(p ^ 1, t + 1); }
        bf16x8 af[4], bfr[4];
#pragma unroll
        for (int m = 0; m < 4; ++m) af[m] = *reinterpret_cast<const bf16x8*>((char*)&lds_a[p][0] + offA[m]);
#pragma unroll
        for (int n = 0; n < 4; ++n) bfr[n] = *reinterpret_cast<const bf16x8*>((char*)&lds_b[p][0] + offB[n]);
#pragma unroll
        for (int m = 0; m < 4; ++m)
#pragma unroll
            for (int n = 0; n < 4; ++n)
                acc[m][n] = __builtin_amdgcn_mfma_f32_16x16x32_bf16(af[m], bfr[n], acc[m][n], 0, 0, 0);
        if (t < NSTEP - 1) { STAGE_A(p ^ 1, t + 1); }
    }
#undef STAGE_A
#undef STAGE_Bm
    const float* vag = ws_f + 1024;
#pragma unroll
    for (int m = 0; m < 4; ++m)
#pragma unroll
        for (int j = 0; j < 4; ++j) {
            int row = row0 + wr * 64 + m * 16 + kg * 4 + j;
            const float* gr = gAG + (size_t)row * DIN;
            float tt = 0.f;
#pragma unroll
            for (int n = 0; n < 4; ++n) {
                int col = col0 + wc * 64 + n * 16 + cl;
                float addv = (ks == 0) ? vag[col] : 0.f;
                tt += gr[col] * (acc[m][n][j] + addv);
            }
            tt += __shfl_xor(tt, 1);
            tt += __shfl_xor(tt, 2);
            tt += __shfl_xor(tt, 4);
            tt += __shfl_xor(tt, 8);
            if (cl == 0) atomicAdd(out + row, 0.5f * tt);
        }
}

extern "C" void kernel_launch(void* const* d_in, const int* in_sizes, int n_in,
                              void* d_out, int out_size, void* d_ws, size_t ws_size,
                              hipStream_t stream) {
    const float* gAB = (const float*)d_in[0];
    const float* gAG = (const float*)d_in[1];
    const float* Wab = (const float*)d_in[2];
    const float* Wag = (const float*)d_in[3];
    const float* bab = (const float*)d_in[4];
    const float* bag = (const float*)d_in[5];
    const float* sAB = (const float*)d_in[6];
    const float* sAG = (const float*)d_in[7];
    float* out = (float*)d_out;

    // ws layout: ws_f 16KB | Mt 2MB | gABh 16MB
    float* ws_f = (float*)d_ws;
    unsigned short* Mt = (unsigned short*)((char*)d_ws + 16384);
    unsigned short* gABh = (unsigned short*)((char*)d_ws + 16384 + (size_t)2 * 1024 * 1024);
    size_t need_full = 16384 + (size_t)18 * 1024 * 1024;
    int precast = (ws_size >= need_full) ? 1 : 0;

    prep_kernel<<<257, 256, 0, stream>>>(Wab, Wag, bab, bag, ws_f);
    mt_kernel<<<256, 512, 0, stream>>>(Wag, Wab, Mt);
    stream_kernel<<<2048, 256, 0, stream>>>(gAB, sAB, sAG, ws_f, gABh, out, precast);
    if (precast)
        gemm8<<<256, 512, 0, stream>>>(gABh, gAG, Mt, ws_f, out);
    else
        gemm_fb<<<1024, 256, 0, stream>>>(gAB, gAG, Mt, ws_f, out);
}

// Round 13
// 74.868 us; speedup vs baseline: 1.7887x; 1.1984x over previous
//
#include <hip/hip_runtime.h>
#include <hip/hip_bf16.h>
#include <stdint.h>

typedef __attribute__((ext_vector_type(8))) short bf16x8;
typedef __attribute__((ext_vector_type(4))) float f32x4;

#define DIN 1024
#define NROWS 8192

__device__ __forceinline__ unsigned short f2bf(float f) {
    union { float f; unsigned u; } v; v.f = f;
    unsigned r = v.u + 0x7FFFu + ((v.u >> 16) & 1u);  // RNE
    return (unsigned short)(r >> 16);
}

// 4-chunk/64B swizzle for Whab/Whag (prep -> mt staging path)
__device__ __forceinline__ int fswz(int r) { return (r ^ (r >> 2)) & 3; }

// 8-chunk/128B storage swizzle for Mt: within each 128B (64-col) group,
// 16B chunks permuted by chunk ^= (R & 7)
__device__ __forceinline__ size_t swz8_byte(int R, int c) {
    return ((size_t)R * DIN + (size_t)(c & ~63)) * 2
         + (size_t)(((((c >> 3) & 7) ^ (R & 7)) << 4))
         + (size_t)((c & 7) * 2);
}

__device__ __forceinline__ void gload_lds16(const void* g, void* l) {
    __builtin_amdgcn_global_load_lds(
        (const __attribute__((address_space(1))) unsigned*)g,
        (__attribute__((address_space(3))) unsigned*)l, 16, 0, 0);
}

// ---- Kernel A: vab/vag/c + cast Wab,Wag -> bf16 (fswz4, feeds mt) ----
__global__ __launch_bounds__(256) void prep_kernel(const float* __restrict__ Wab,
                                                   const float* __restrict__ Wag,
                                                   const float* __restrict__ bab,
                                                   const float* __restrict__ bag,
                                                   float* __restrict__ ws_f,
                                                   unsigned short* __restrict__ Whab,
                                                   unsigned short* __restrict__ Whag) {
    int b = blockIdx.x;
    int wave = threadIdx.x >> 6, lane = threadIdx.x & 63;
    if (b == 256) {
        if (wave == 0) {
            float acc = 0.f;
            for (int j = lane; j < DIN; j += 64) acc += bab[j] * bag[j];
            for (int off = 32; off; off >>= 1) acc += __shfl_xor(acc, off);
            if (lane == 0) ws_f[2048] = acc;
        }
        return;
    }
    int r = b * 4 + wave;
    int fr = fswz(r);
    {
        const float* wrow = Wab + (size_t)r * DIN;
        char* hrow = (char*)Whab + (size_t)r * DIN * 2;
        float acc = 0.f;
#pragma unroll
        for (int it = 0; it < 4; ++it) {
            int col = it * 256 + lane * 4;
            float4 w = *reinterpret_cast<const float4*>(wrow + col);
            float4 bv = *reinterpret_cast<const float4*>(bag + col);
            acc += w.x * bv.x + w.y * bv.y + w.z * bv.z + w.w * bv.w;
            ushort4 h; h.x = f2bf(w.x); h.y = f2bf(w.y); h.z = f2bf(w.z); h.w = f2bf(w.w);
            *reinterpret_cast<ushort4*>(hrow + (col & ~31) * 2 + ((((col >> 3) & 3) ^ fr) << 4) + (col & 7) * 2) = h;
        }
        for (int off = 32; off; off >>= 1) acc += __shfl_xor(acc, off);
        if (lane == 0) ws_f[r] = acc;          // vab
    }
    {
        const float* wrow = Wag + (size_t)r * DIN;
        char* hrow = (char*)Whag + (size_t)r * DIN * 2;
        float acc = 0.f;
#pragma unroll
        for (int it = 0; it < 4; ++it) {
            int col = it * 256 + lane * 4;
            float4 w = *reinterpret_cast<const float4*>(wrow + col);
            float4 bv = *reinterpret_cast<const float4*>(bab + col);
            acc += w.x * bv.x + w.y * bv.y + w.z * bv.z + w.w * bv.w;
            ushort4 h; h.x = f2bf(w.x); h.y = f2bf(w.y); h.z = f2bf(w.z); h.w = f2bf(w.w);
            *reinterpret_cast<ushort4*>(hrow + (col & ~31) * 2 + ((((col >> 3) & 3) ^ fr) << 4) + (col & 7) * 2) = h;
        }
        for (int off = 32; off; off >>= 1) acc += __shfl_xor(acc, off);
        if (lane == 0) ws_f[1024 + r] = acc;   // vag
    }
}

// ---- Kernel B: Mt[l,k] = Wag[l,:].Wab[k,:]; bf16 Wh input via gload_lds,
//      fswz4 LDS reads, Mt output in swz8 (R9-proven) ----
__global__ __launch_bounds__(512) void mt_kernel(const unsigned short* __restrict__ Whag,
                                                 const unsigned short* __restrict__ Whab,
                                                 unsigned short* __restrict__ Mt) {
    __shared__ unsigned short sm[2][2][2][2048];   // [grp][buf][op][64*32] = 32 KB
    int tid = threadIdx.x;
    int wave = tid >> 6, grp = wave >> 2, w4 = wave & 3;
    int lane = tid & 63, kg = lane >> 4, cl = lane & 15;
    int wr = w4 >> 1, wc = w4 & 1;
    int br = blockIdx.x >> 4, bc = blockIdx.x & 15;
    int u = tid & 255, urow = u >> 2, uchunk = u & 3;

    const char* Abase = (const char*)Whag + ((size_t)(br * 64 + urow) * DIN + grp * 512) * 2 + uchunk * 16;
    const char* Bbase = (const char*)Whab + ((size_t)(bc * 64 + urow) * DIN + grp * 512) * 2 + uchunk * 16;

    int offA[2], offB[2];
#pragma unroll
    for (int m = 0; m < 2; ++m) { int row = wr * 32 + m * 16 + cl; offA[m] = row * 32 + ((kg ^ fswz(row)) << 3); }
#pragma unroll
    for (int n = 0; n < 2; ++n) { int row = wc * 32 + n * 16 + cl; offB[n] = row * 32 + ((kg ^ fswz(row)) << 3); }

    f32x4 acc[2][2] = {};
    gload_lds16(Abase, &sm[grp][0][0][u * 8]);
    gload_lds16(Bbase, &sm[grp][0][1][u * 8]);
    for (int t = 0; t < 16; ++t) {
        int p = t & 1;
        __syncthreads();
        if (t < 15) {
            gload_lds16(Abase + (t + 1) * 64, &sm[grp][p ^ 1][0][u * 8]);
            gload_lds16(Bbase + (t + 1) * 64, &sm[grp][p ^ 1][1][u * 8]);
        }
        bf16x8 af[2], bfr[2];
#pragma unroll
        for (int m = 0; m < 2; ++m) af[m] = *reinterpret_cast<const bf16x8*>(&sm[grp][p][0][offA[m]]);
#pragma unroll
        for (int n = 0; n < 2; ++n) bfr[n] = *reinterpret_cast<const bf16x8*>(&sm[grp][p][1][offB[n]]);
        __builtin_amdgcn_s_setprio(1);
#pragma unroll
        for (int m = 0; m < 2; ++m)
#pragma unroll
            for (int n = 0; n < 2; ++n)
                acc[m][n] = __builtin_amdgcn_mfma_f32_16x16x32_bf16(af[m], bfr[n], acc[m][n], 0, 0, 0);
        __builtin_amdgcn_s_setprio(0);
    }
    __syncthreads();
    float* red = (float*)sm;   // [64][68] padded
    if (grp == 1) {
#pragma unroll
        for (int m = 0; m < 2; ++m)
#pragma unroll
            for (int n = 0; n < 2; ++n)
#pragma unroll
                for (int j = 0; j < 4; ++j)
                    red[(wr * 32 + m * 16 + kg * 4 + j) * 68 + wc * 32 + n * 16 + cl] = acc[m][n][j];
    }
    __syncthreads();
    if (grp == 0) {
#pragma unroll
        for (int m = 0; m < 2; ++m)
#pragma unroll
            for (int n = 0; n < 2; ++n)
#pragma unroll
                for (int j = 0; j < 4; ++j) {
                    int rl = wr * 32 + m * 16 + kg * 4 + j, cll = wc * 32 + n * 16 + cl;
                    float v = acc[m][n][j] + red[rl * 68 + cll];
                    int R = br * 64 + rl, C = bc * 64 + cll;
                    *(unsigned short*)((char*)Mt + swz8_byte(R, C)) = f2bf(v);
                }
    }
}

// ---- Kernel C (fused, staggered roles): every block does a coalesced 8-row
//      stream slice (h2 + Term2 + c) AND a 128^2 GEMM tile (Term1 + Term3);
//      order alternates by (b>>3)&1 so ~half the resident blocks stream while
//      the other half GEMM -> stream BW fills the GEMM's latency stalls. ----
__global__ __launch_bounds__(256, 4) void fused_kernel(const float* __restrict__ gAB,
                                                       const float* __restrict__ gAG,
                                                       const float* __restrict__ sAB,
                                                       const float* __restrict__ sAG,
                                                       const unsigned short* __restrict__ Mt,
                                                       const float* __restrict__ ws_f,
                                                       float* __restrict__ out) {
    __shared__ unsigned short lds_a[2][128 * 32];
    __shared__ unsigned short lds_b[2][128 * 32];
    constexpr int KSPLIT = 2, KLEN = DIN / KSPLIT, NSTEP = KLEN / 32;
    int b = blockIdx.x;
    int x = b & 7, s = b >> 3;
    int rblk = x + 8 * (s & 7);
    int u2 = s >> 3;
    int ks = u2 & (KSPLIT - 1);
    int cblk = u2 / KSPLIT;
    int tid = threadIdx.x, wave = tid >> 6, lane = tid & 63;
    int streamFirst = (s & 1);

    // ---------------- stream slice: rows [b*8, b*8+8), 2 rows/wave ----------------
    const float* vab = ws_f;
    float cbias = ws_f[2048];
    auto do_stream = [&]() {
#pragma unroll
        for (int rr = 0; rr < 2; ++rr) {
            int row = b * 8 + wave * 2 + rr;
            const float* ga = gAB + (size_t)row * DIN;
            const float* sa = sAB + (size_t)row * DIN;
            const float* sg = sAG + (size_t)row * DIN;
            float acc = 0.f;
#pragma unroll
            for (int cc = 0; cc < 4; ++cc) {
                int col = cc * 256 + lane * 4;
                float4 a = *reinterpret_cast<const float4*>(ga + col);
                float4 x4 = *reinterpret_cast<const float4*>(sa + col);
                float4 y4 = *reinterpret_cast<const float4*>(sg + col);
                float4 v = *reinterpret_cast<const float4*>(vab + col);
                acc += x4.x * y4.x + x4.y * y4.y + x4.z * y4.z + x4.w * y4.w;
                acc += a.x * v.x + a.y * v.y + a.z * v.z + a.w * v.w;
            }
#pragma unroll
            for (int off = 32; off; off >>= 1) acc += __shfl_xor(acc, off);
            if (lane == 0) atomicAdd(out + row, 0.5f * (acc + cbias));
        }
    };

    if (streamFirst) do_stream();

    // ---------------- GEMM tile (R4-class 2-phase, fp32-A staging) ----------------
    {
        int wr = wave >> 1, wc = wave & 1;
        int kg = lane >> 4, cl = lane & 15;
        int row0 = rblk * 128, col0 = cblk * 128;

        int offA[4], offB[4];
#pragma unroll
        for (int m = 0; m < 4; ++m) { int row = wr * 64 + m * 16 + cl; offA[m] = row * 64 + ((kg ^ (row & 3)) << 4); }
#pragma unroll
        for (int n = 0; n < 4; ++n) { int row = wc * 64 + n * 16 + cl; offB[n] = row * 64 + ((kg ^ (row & 3)) << 4); }

        const float* Af = gAB + (size_t)row0 * DIN + ks * KLEN;
        const char* Bb = (const char*)Mt + ((size_t)col0 * DIN + ks * KLEN) * 2;

        f32x4 acc[4][4] = {};
        float4 ra[4];
#define STAGE_A(buf, t)                                                             \
        _Pragma("unroll")                                                           \
        for (int it = 0; it < 4; ++it) {                                            \
            int u = tid + it * 256, row_ = u >> 3, c4 = u & 7;                      \
            ra[it] = *reinterpret_cast<const float4*>(Af + (size_t)row_ * DIN + (t) * 32 + c4 * 4); \
        }                                                                           \
        _Pragma("unroll")                                                           \
        for (int it = 0; it < 4; ++it) {                                            \
            int u = tid + it * 256, row_ = u >> 3, c4 = u & 7;                      \
            ushort4 h; h.x = f2bf(ra[it].x); h.y = f2bf(ra[it].y); h.z = f2bf(ra[it].z); h.w = f2bf(ra[it].w); \
            *reinterpret_cast<ushort4*>((char*)&lds_a[buf][0] + row_ * 64 +         \
                                        (((c4 >> 1) ^ (row_ & 3)) << 4) + (c4 & 1) * 8) = h; \
        }
#define STAGE_Bm(buf, t)                                                            \
        _Pragma("unroll")                                                           \
        for (int it = 0; it < 2; ++it) {                                            \
            int u = tid + it * 256, row_ = u >> 2, s_ = u & 3;                      \
            int pg = ((((t) & 1) << 2) ^ (row_ & 4)) | s_;                          \
            gload_lds16(Bb + (size_t)row_ * 2048 + ((t) >> 1) * 128 + pg * 16,      \
                        (char*)&lds_b[buf][0] + u * 16);                            \
        }
        STAGE_A(0, 0);
        STAGE_Bm(0, 0);
        for (int t = 0; t < NSTEP; ++t) {
            int p = t & 1;
            __syncthreads();
            if (t < NSTEP - 1) { STAGE_Bm(p ^ 1, t + 1); }
            bf16x8 af[4], bfr[4];
#pragma unroll
            for (int m = 0; m < 4; ++m) af[m] = *reinterpret_cast<const bf16x8*>((char*)&lds_a[p][0] + offA[m]);
#pragma unroll
            for (int n = 0; n < 4; ++n) bfr[n] = *reinterpret_cast<const bf16x8*>((char*)&lds_b[p][0] + offB[n]);
            __builtin_amdgcn_s_setprio(1);
#pragma unroll
            for (int m = 0; m < 4; ++m)
#pragma unroll
                for (int n = 0; n < 4; ++n)
                    acc[m][n] = __builtin_amdgcn_mfma_f32_16x16x32_bf16(af[m], bfr[n], acc[m][n], 0, 0, 0);
            __builtin_amdgcn_s_setprio(0);
            if (t < NSTEP - 1) { STAGE_A(p ^ 1, t + 1); }
        }
#undef STAGE_A
#undef STAGE_Bm

        // epilogue: Term1 (all ks) + Term3 (ks==0 only)
        const float* vag = ws_f + 1024;
#pragma unroll
        for (int m = 0; m < 4; ++m)
#pragma unroll
            for (int j = 0; j < 4; ++j) {
                int row = row0 + wr * 64 + m * 16 + kg * 4 + j;
                const float* gr = gAG + (size_t)row * DIN;
                float tt = 0.f;
#pragma unroll
                for (int n = 0; n < 4; ++n) {
                    int col = col0 + wc * 64 + n * 16 + cl;
                    float addv = (ks == 0) ? vag[col] : 0.f;
                    tt += gr[col] * (acc[m][n][j] + addv);
                }
                tt += __shfl_xor(tt, 1);
                tt += __shfl_xor(tt, 2);
                tt += __shfl_xor(tt, 4);
                tt += __shfl_xor(tt, 8);
                if (cl == 0) atomicAdd(out + row, 0.5f * tt);
            }
    }

    if (!streamFirst) do_stream();
}

extern "C" void kernel_launch(void* const* d_in, const int* in_sizes, int n_in,
                              void* d_out, int out_size, void* d_ws, size_t ws_size,
                              hipStream_t stream) {
    const float* gAB = (const float*)d_in[0];
    const float* gAG = (const float*)d_in[1];
    const float* Wab = (const float*)d_in[2];
    const float* Wag = (const float*)d_in[3];
    const float* bab = (const float*)d_in[4];
    const float* bag = (const float*)d_in[5];
    const float* sAB = (const float*)d_in[6];
    const float* sAG = (const float*)d_in[7];
    float* out = (float*)d_out;

    // ws layout: ws_f 16KB | Mt 2MB | Whag 2MB | Whab 2MB
    float* ws_f = (float*)d_ws;
    char* base = (char*)d_ws + 16384;
    unsigned short* Mt = (unsigned short*)base;
    unsigned short* Whag = (unsigned short*)(base + (size_t)2 * 1024 * 1024);
    unsigned short* Whab = (unsigned short*)(base + (size_t)4 * 1024 * 1024);

    hipMemsetAsync(d_out, 0, (size_t)out_size * sizeof(float), stream);
    prep_kernel<<<257, 256, 0, stream>>>(Wab, Wag, bab, bag, ws_f, Whab, Whag);
    mt_kernel<<<256, 512, 0, stream>>>(Whag, Whab, Mt);
    fused_kernel<<<1024, 256, 0, stream>>>(gAB, gAG, sAB, sAG, Mt, ws_f, out);
}

// Round 14
// 61.419 us; speedup vs baseline: 2.1804x; 1.2190x over previous
//
#include <hip/hip_runtime.h>
#include <hip/hip_bf16.h>
#include <stdint.h>

typedef __attribute__((ext_vector_type(8))) short bf16x8;
typedef __attribute__((ext_vector_type(4))) float f32x4;

#define DIN 1024
#define NROWS 8192

__device__ __forceinline__ unsigned short f2bf(float f) {
    union { float f; unsigned u; } v; v.f = f;
    unsigned r = v.u + 0x7FFFu + ((v.u >> 16) & 1u);  // RNE
    return (unsigned short)(r >> 16);
}

__device__ __forceinline__ int fswz(int r) { return (r ^ (r >> 2)) & 3; }

// byte offset of bf16 element (R,c) in row-major [*,1024] stored with 16B-chunk
// XOR swizzle (chunk ^= fswz(R)) within 64B groups
__device__ __forceinline__ size_t swz_byte(int R, int c) {
    return ((size_t)R * DIN + (size_t)(c & ~31)) * 2
         + (size_t)((((c >> 3) & 3) ^ fswz(R)) << 4)
         + (size_t)((c & 7) * 2);
}

__device__ __forceinline__ void gload_lds16(const void* g, void* l) {
    __builtin_amdgcn_global_load_lds(
        (const __attribute__((address_space(1))) unsigned*)g,
        (__attribute__((address_space(3))) unsigned*)l, 16, 0, 0);
}

// ---- Kernel A: vab/vag/c + cast Wab,Wag -> bf16 (fswz4) ----
__global__ __launch_bounds__(256) void prep_kernel(const float* __restrict__ Wab,
                                                   const float* __restrict__ Wag,
                                                   const float* __restrict__ bab,
                                                   const float* __restrict__ bag,
                                                   float* __restrict__ ws_f,
                                                   unsigned short* __restrict__ Whab,
                                                   unsigned short* __restrict__ Whag) {
    int b = blockIdx.x;
    int wave = threadIdx.x >> 6, lane = threadIdx.x & 63;
    if (b == 256) {
        if (wave == 0) {
            float acc = 0.f;
            for (int j = lane; j < DIN; j += 64) acc += bab[j] * bag[j];
            for (int off = 32; off; off >>= 1) acc += __shfl_xor(acc, off);
            if (lane == 0) ws_f[2048] = acc;
        }
        return;
    }
    int r = b * 4 + wave;
    int fr = fswz(r);
    {
        const float* wrow = Wab + (size_t)r * DIN;
        char* hrow = (char*)Whab + (size_t)r * DIN * 2;
        float acc = 0.f;
#pragma unroll
        for (int it = 0; it < 4; ++it) {
            int col = it * 256 + lane * 4;
            float4 w = *reinterpret_cast<const float4*>(wrow + col);
            float4 bv = *reinterpret_cast<const float4*>(bag + col);
            acc += w.x * bv.x + w.y * bv.y + w.z * bv.z + w.w * bv.w;
            ushort4 h; h.x = f2bf(w.x); h.y = f2bf(w.y); h.z = f2bf(w.z); h.w = f2bf(w.w);
            *reinterpret_cast<ushort4*>(hrow + (col & ~31) * 2 + ((((col >> 3) & 3) ^ fr) << 4) + (col & 7) * 2) = h;
        }
        for (int off = 32; off; off >>= 1) acc += __shfl_xor(acc, off);
        if (lane == 0) ws_f[r] = acc;          // vab
    }
    {
        const float* wrow = Wag + (size_t)r * DIN;
        char* hrow = (char*)Whag + (size_t)r * DIN * 2;
        float acc = 0.f;
#pragma unroll
        for (int it = 0; it < 4; ++it) {
            int col = it * 256 + lane * 4;
            float4 w = *reinterpret_cast<const float4*>(wrow + col);
            float4 bv = *reinterpret_cast<const float4*>(bab + col);
            acc += w.x * bv.x + w.y * bv.y + w.z * bv.z + w.w * bv.w;
            ushort4 h; h.x = f2bf(w.x); h.y = f2bf(w.y); h.z = f2bf(w.z); h.w = f2bf(w.w);
            *reinterpret_cast<ushort4*>(hrow + (col & ~31) * 2 + ((((col >> 3) & 3) ^ fr) << 4) + (col & 7) * 2) = h;
        }
        for (int off = 32; off; off >>= 1) acc += __shfl_xor(acc, off);
        if (lane == 0) ws_f[1024 + r] = acc;   // vag
    }
}

// ---- Kernel B (combo): blocks [0,256) = mt role (dispatched FIRST, hides under
//      stream); blocks [256,2304) = stream role (R8-exact). One dispatch saves
//      mt's ~6 us serial slot. ----
__global__ __launch_bounds__(256) void combo_kernel(const unsigned short* __restrict__ Whag,
                                                    const unsigned short* __restrict__ Whab,
                                                    unsigned short* __restrict__ Mt,
                                                    const float* __restrict__ gAB,
                                                    const float* __restrict__ sAB,
                                                    const float* __restrict__ sAG,
                                                    const float* __restrict__ ws_f,
                                                    unsigned short* __restrict__ gABh,
                                                    float* __restrict__ out,
                                                    int writecast) {
    __shared__ unsigned short sm[2][2][2][2048];   // [grp][buf][op][64*32] = 32 KB (mt role)
    int b = blockIdx.x;
    int tid = threadIdx.x, wave = tid >> 6, lane = tid & 63;

    if (b < 256) {
        // ---------------- mt role: Mt[l,k] = Wag[l,:].Wab[k,:], 64x64 tile ----------------
        // 4 waves = 2 K-groups x 2 waves; 16 steps of BK=32 per group; LDS split-K reduce.
        int grp = wave >> 1, w2 = wave & 1;
        int kg = lane >> 4, cl = lane & 15;
        int br = b >> 4, bc = b & 15;
        int u = tid & 127;

        const char* Abase = (const char*)Whag + ((size_t)(br * 64) * DIN + grp * 512) * 2;
        const char* Bbase = (const char*)Whab + ((size_t)(bc * 64) * DIN + grp * 512) * 2;

        int offA[2], offB[4];   // short-unit offsets
#pragma unroll
        for (int m = 0; m < 2; ++m) { int row = w2 * 32 + m * 16 + cl; offA[m] = row * 32 + ((kg ^ fswz(row)) << 3); }
#pragma unroll
        for (int n = 0; n < 4; ++n) { int row = n * 16 + cl; offB[n] = row * 32 + ((kg ^ fswz(row)) << 3); }

        f32x4 acc[2][4] = {};
        // stage: A,B each 256 16B-units per (grp,buf); 128 threads -> 2 iters each.
        // fswz4 64B groups == one BK=32 row slice, so linear copy preserves the swizzle.
#define STAGE_MT(buf, t)                                                            \
        _Pragma("unroll")                                                           \
        for (int it = 0; it < 2; ++it) {                                            \
            int un = u + it * 128, urow = un >> 2, uc = un & 3;                     \
            gload_lds16(Abase + (size_t)urow * 2048 + (t) * 64 + uc * 16,           \
                        &sm[grp][buf][0][un * 8]);                                  \
            gload_lds16(Bbase + (size_t)urow * 2048 + (t) * 64 + uc * 16,           \
                        &sm[grp][buf][1][un * 8]);                                  \
        }
        STAGE_MT(0, 0);
        for (int t = 0; t < 16; ++t) {
            int p = t & 1;
            __syncthreads();
            if (t < 15) { STAGE_MT(p ^ 1, t + 1); }
            bf16x8 af[2], bfr[4];
#pragma unroll
            for (int m = 0; m < 2; ++m) af[m] = *reinterpret_cast<const bf16x8*>(&sm[grp][p][0][offA[m]]);
#pragma unroll
            for (int n = 0; n < 4; ++n) bfr[n] = *reinterpret_cast<const bf16x8*>(&sm[grp][p][1][offB[n]]);
            __builtin_amdgcn_s_setprio(1);
#pragma unroll
            for (int m = 0; m < 2; ++m)
#pragma unroll
                for (int n = 0; n < 4; ++n)
                    acc[m][n] = __builtin_amdgcn_mfma_f32_16x16x32_bf16(af[m], bfr[n], acc[m][n], 0, 0, 0);
            __builtin_amdgcn_s_setprio(0);
        }
#undef STAGE_MT
        __syncthreads();
        float* red = (float*)sm;   // [64][68] padded, 17.4 KB
        if (grp == 1) {
#pragma unroll
            for (int m = 0; m < 2; ++m)
#pragma unroll
                for (int n = 0; n < 4; ++n)
#pragma unroll
                    for (int j = 0; j < 4; ++j)
                        red[(w2 * 32 + m * 16 + kg * 4 + j) * 68 + n * 16 + cl] = acc[m][n][j];
        }
        __syncthreads();
        if (grp == 0) {
#pragma unroll
            for (int m = 0; m < 2; ++m)
#pragma unroll
                for (int n = 0; n < 4; ++n)
#pragma unroll
                    for (int j = 0; j < 4; ++j) {
                        int rl = w2 * 32 + m * 16 + kg * 4 + j, cll = n * 16 + cl;
                        float v = acc[m][n][j] + red[rl * 68 + cll];
                        int R = br * 64 + rl, C = bc * 64 + cll;
                        *(unsigned short*)((char*)Mt + swz_byte(R, C)) = f2bf(v);
                    }
        }
        return;
    }

    // ---------------- stream role (R8-exact): h2 + Term2 + c; cast gAB -> gABh ----------------
    int row = (b - 256) * 4 + wave;
    const float* ga = gAB + (size_t)row * DIN;
    const float* sa = sAB + (size_t)row * DIN;
    const float* sg = sAG + (size_t)row * DIN;
    char* gh = (char*)gABh + (size_t)row * DIN * 2;
    int fr = fswz(row);
    float acc = 0.f;
#pragma unroll
    for (int cc = 0; cc < 4; ++cc) {
        int col = cc * 256 + lane * 4;
        float4 a = *reinterpret_cast<const float4*>(ga + col);
        float4 x = *reinterpret_cast<const float4*>(sa + col);
        float4 y = *reinterpret_cast<const float4*>(sg + col);
        float4 v = *reinterpret_cast<const float4*>(ws_f + col);   // vab
        acc += x.x * y.x + x.y * y.y + x.z * y.z + x.w * y.w;
        acc += a.x * v.x + a.y * v.y + a.z * v.z + a.w * v.w;
        if (writecast) {
            ushort4 h; h.x = f2bf(a.x); h.y = f2bf(a.y); h.z = f2bf(a.z); h.w = f2bf(a.w);
            *reinterpret_cast<ushort4*>(gh + (col & ~31) * 2 + ((((col >> 3) & 3) ^ fr) << 4) + (col & 7) * 2) = h;
        }
    }
#pragma unroll
    for (int off = 32; off; off >>= 1) acc += __shfl_xor(acc, off);
    if (lane == 0) out[row] = 0.5f * (acc + ws_f[2048]);
}

// ---- Kernel C: P = gAB @ Mt^T fused Term1+Term3 (R8-exact, stage-after-barrier) ----
template <int PRECAST, int KSPLIT>
__global__ __launch_bounds__(256, 4) void gemm_kernel(const float* __restrict__ gAB,
                                                      const unsigned short* __restrict__ gABh,
                                                      const float* __restrict__ gAG,
                                                      const unsigned short* __restrict__ Mt,
                                                      const float* __restrict__ ws_f,
                                                      float* __restrict__ out) {
    __shared__ unsigned short lds_a[2][128 * 32];
    __shared__ unsigned short lds_b[2][128 * 32];
    constexpr int KLEN = DIN / KSPLIT;
    constexpr int NSTEP = KLEN / 32;
    int b = blockIdx.x;
    int x = b & 7, s = b >> 3;
    int rblk = x + 8 * (s & 7);
    int u2 = s >> 3;
    int ks = u2 & (KSPLIT - 1);
    int cblk = u2 / KSPLIT;
    int tid = threadIdx.x, wave = tid >> 6, lane = tid & 63;
    int wr = wave >> 1, wc = wave & 1;
    int kg = lane >> 4, cl = lane & 15;
    int row0 = rblk * 128, col0 = cblk * 128;

    int offA[4], offB[4];
#pragma unroll
    for (int m = 0; m < 4; ++m) { int row = wr * 64 + m * 16 + cl; offA[m] = row * 32 + ((kg ^ fswz(row)) << 3); }
#pragma unroll
    for (int n = 0; n < 4; ++n) { int row = wc * 64 + n * 16 + cl; offB[n] = row * 32 + ((kg ^ fswz(row)) << 3); }

    size_t kofs = (size_t)(ks * KLEN) * 2;
    const char* Ab = (const char*)gABh + (size_t)row0 * DIN * 2 + kofs;
    const char* Bb = (const char*)Mt + (size_t)col0 * DIN * 2 + kofs;
    int u0 = tid, u1 = tid + 256;
    size_t a0 = (size_t)(u0 >> 2) * (DIN * 2) + (u0 & 3) * 16;
    size_t a1 = (size_t)(u1 >> 2) * (DIN * 2) + (u1 & 3) * 16;

    f32x4 acc[4][4] = {};
    float4 ra[4];
    if (PRECAST) {
        gload_lds16(Ab + a0, (char*)&lds_a[0][0] + u0 * 16);
        gload_lds16(Ab + a1, (char*)&lds_a[0][0] + u1 * 16);
        gload_lds16(Bb + a0, (char*)&lds_b[0][0] + u0 * 16);
        gload_lds16(Bb + a1, (char*)&lds_b[0][0] + u1 * 16);

        for (int t = 0; t < NSTEP; ++t) {
            int p = t & 1;
            __syncthreads();
            if (t < NSTEP - 1) {
                gload_lds16(Ab + a0 + (t + 1) * 64, (char*)&lds_a[p ^ 1][0] + u0 * 16);
                gload_lds16(Ab + a1 + (t + 1) * 64, (char*)&lds_a[p ^ 1][0] + u1 * 16);
                gload_lds16(Bb + a0 + (t + 1) * 64, (char*)&lds_b[p ^ 1][0] + u0 * 16);
                gload_lds16(Bb + a1 + (t + 1) * 64, (char*)&lds_b[p ^ 1][0] + u1 * 16);
            }
            bf16x8 af[4], bfr[4];
#pragma unroll
            for (int m = 0; m < 4; ++m) af[m] = *reinterpret_cast<const bf16x8*>(&lds_a[p][offA[m]]);
#pragma unroll
            for (int n = 0; n < 4; ++n) bfr[n] = *reinterpret_cast<const bf16x8*>(&lds_b[p][offB[n]]);
            __builtin_amdgcn_s_setprio(1);
#pragma unroll
            for (int m = 0; m < 4; ++m)
#pragma unroll
                for (int n = 0; n < 4; ++n)
                    acc[m][n] = __builtin_amdgcn_mfma_f32_16x16x32_bf16(af[m], bfr[n], acc[m][n], 0, 0, 0);
            __builtin_amdgcn_s_setprio(0);
        }
    } else {
#pragma unroll
        for (int it = 0; it < 4; ++it) {
            int u = tid + it * 256;
            ra[it] = *reinterpret_cast<const float4*>(gAB + (size_t)(row0 + (u >> 3)) * DIN + ks * KLEN + (u & 7) * 4);
        }
#pragma unroll
        for (int it = 0; it < 4; ++it) {
            int u = tid + it * 256, row = u >> 3, c4 = u & 7;
            ushort4 h; h.x = f2bf(ra[it].x); h.y = f2bf(ra[it].y); h.z = f2bf(ra[it].z); h.w = f2bf(ra[it].w);
            *reinterpret_cast<ushort4*>((char*)&lds_a[0][0] + row * 64 + ((((c4 >> 1) ^ fswz(row))) << 4) + (c4 & 1) * 8) = h;
        }
        gload_lds16(Bb + a0, (char*)&lds_b[0][0] + u0 * 16);
        gload_lds16(Bb + a1, (char*)&lds_b[0][0] + u1 * 16);
        for (int t = 0; t < NSTEP; ++t) {
            int p = t & 1;
            __syncthreads();
            if (t < NSTEP - 1) {
#pragma unroll
                for (int it = 0; it < 4; ++it) {
                    int u = tid + it * 256;
                    ra[it] = *reinterpret_cast<const float4*>(gAB + (size_t)(row0 + (u >> 3)) * DIN + ks * KLEN + (t + 1) * 32 + (u & 7) * 4);
                }
                gload_lds16(Bb + a0 + (t + 1) * 64, (char*)&lds_b[p ^ 1][0] + u0 * 16);
                gload_lds16(Bb + a1 + (t + 1) * 64, (char*)&lds_b[p ^ 1][0] + u1 * 16);
            }
            bf16x8 af[4], bfr[4];
#pragma unroll
            for (int m = 0; m < 4; ++m) af[m] = *reinterpret_cast<const bf16x8*>(&lds_a[p][offA[m]]);
#pragma unroll
            for (int n = 0; n < 4; ++n) bfr[n] = *reinterpret_cast<const bf16x8*>(&lds_b[p][offB[n]]);
#pragma unroll
            for (int m = 0; m < 4; ++m)
#pragma unroll
                for (int n = 0; n < 4; ++n)
                    acc[m][n] = __builtin_amdgcn_mfma_f32_16x16x32_bf16(af[m], bfr[n], acc[m][n], 0, 0, 0);
            if (t < NSTEP - 1) {
#pragma unroll
                for (int it = 0; it < 4; ++it) {
                    int u = tid + it * 256, row = u >> 3, c4 = u & 7;
                    ushort4 h; h.x = f2bf(ra[it].x); h.y = f2bf(ra[it].y); h.z = f2bf(ra[it].z); h.w = f2bf(ra[it].w);
                    *reinterpret_cast<ushort4*>((char*)&lds_a[p ^ 1][0] + row * 64 + ((((c4 >> 1) ^ fswz(row))) << 4) + (c4 & 1) * 8) = h;
                }
            }
        }
    }

    const float* vag = ws_f + 1024;
#pragma unroll
    for (int m = 0; m < 4; ++m)
#pragma unroll
        for (int j = 0; j < 4; ++j) {
            int row = row0 + wr * 64 + m * 16 + kg * 4 + j;
            const float* gr = gAG + (size_t)row * DIN;
            float t = 0.f;
#pragma unroll
            for (int n = 0; n < 4; ++n) {
                int col = col0 + wc * 64 + n * 16 + cl;
                float addv = (ks == 0) ? vag[col] : 0.f;
                t += gr[col] * (acc[m][n][j] + addv);
            }
            t += __shfl_xor(t, 1);
            t += __shfl_xor(t, 2);
            t += __shfl_xor(t, 4);
            t += __shfl_xor(t, 8);
            if (cl == 0) atomicAdd(out + row, 0.5f * t);
        }
}

extern "C" void kernel_launch(void* const* d_in, const int* in_sizes, int n_in,
                              void* d_out, int out_size, void* d_ws, size_t ws_size,
                              hipStream_t stream) {
    const float* gAB = (const float*)d_in[0];
    const float* gAG = (const float*)d_in[1];
    const float* Wab = (const float*)d_in[2];
    const float* Wag = (const float*)d_in[3];
    const float* bab = (const float*)d_in[4];
    const float* bag = (const float*)d_in[5];
    const float* sAB = (const float*)d_in[6];
    const float* sAG = (const float*)d_in[7];
    float* out = (float*)d_out;

    // ws layout: ws_f 16KB | Mt 2MB | Whag 2MB | Whab 2MB | gABh 16MB
    float* ws_f = (float*)d_ws;
    char* base = (char*)d_ws + 16384;
    unsigned short* Mt = (unsigned short*)base;
    unsigned short* Whag = (unsigned short*)(base + (size_t)2 * 1024 * 1024);
    unsigned short* Whab = (unsigned short*)(base + (size_t)4 * 1024 * 1024);
    unsigned short* gABh = (unsigned short*)(base + (size_t)6 * 1024 * 1024);
    size_t need_full = 16384 + (size_t)22 * 1024 * 1024;
    int precast = (ws_size >= need_full) ? 1 : 0;

    prep_kernel<<<257, 256, 0, stream>>>(Wab, Wag, bab, bag, ws_f, Whab, Whag);
    combo_kernel<<<2304, 256, 0, stream>>>(Whag, Whab, Mt, gAB, sAB, sAG, ws_f, gABh, out, precast);
    if (precast)
        gemm_kernel<1, 2><<<1024, 256, 0, stream>>>(gAB, gABh, gAG, Mt, ws_f, out);
    else
        gemm_kernel<0, 2><<<1024, 256, 0, stream>>>(gAB, gABh, gAG, Mt, ws_f, out);
}